// Round 1
// baseline (668.250 us; speedup 1.0000x reference)
//
#include <hip/hip_runtime.h>
#include <math.h>

#define B_ 16
#define D_ 128
#define LC_ 2048
#define LQ_ 512
#define NEG_ (-1e30f)

// ---------------------------------------------------------------------------
// K1: sub0[b,c] = sum_d C[b,d,c]*w4C[d];  sub1[b,q] = sum_d Q[b,d,q]*w4Q[d] + bias
// grid 160 = 128 (sub0) + 32 (sub1), block 256
// ---------------------------------------------------------------------------
__global__ __launch_bounds__(256) void k_subs(
        const float* __restrict__ C, const float* __restrict__ Q,
        const float* __restrict__ w4C, const float* __restrict__ w4Q,
        const float* __restrict__ bias,
        float* __restrict__ sub0, float* __restrict__ sub1) {
    int bid = blockIdx.x;
    const int nb0 = B_ * (LC_ / 256);   // 128
    if (bid < nb0) {
        int b = bid / (LC_ / 256);
        int c = (bid % (LC_ / 256)) * 256 + threadIdx.x;
        const float* Cb = C + (size_t)b * D_ * LC_;
        float acc = 0.f;
        #pragma unroll 8
        for (int d = 0; d < D_; ++d) acc += Cb[(size_t)d * LC_ + c] * w4C[d];
        sub0[b * LC_ + c] = acc;
    } else {
        int id = bid - nb0;
        int b = id / (LQ_ / 256);
        int q = (id % (LQ_ / 256)) * 256 + threadIdx.x;
        const float* Qb = Q + (size_t)b * D_ * LQ_;
        float acc = bias[0];
        #pragma unroll 8
        for (int d = 0; d < D_; ++d) acc += Qb[(size_t)d * LQ_ + q] * w4Q[d];
        sub1[b * LQ_ + q] = acc;
    }
}

// ---------------------------------------------------------------------------
// K2: S[b,c,q] = sum_d (C[b,d,c]*w4mlu[d]) * Q[b,d,q] + sub0[c] + sub1[q]
// tile 64c x 128q, BK=32, 256 thr, micro 4c(consec) x 8q(strided16)
// grid (LQ/128, LC/64, B)
// ---------------------------------------------------------------------------
__global__ __launch_bounds__(256) void k_sgemm(
        const float* __restrict__ C, const float* __restrict__ Q,
        const float* __restrict__ w4mlu,
        const float* __restrict__ sub0, const float* __restrict__ sub1,
        float* __restrict__ S) {
    __shared__ float As[32][64];    // [k][c]
    __shared__ float Bs[32][128];   // [k][q]
    const int b  = blockIdx.z;
    const int c0 = blockIdx.y * 64;
    const int q0 = blockIdx.x * 128;
    const float* Cb = C + (size_t)b * D_ * LC_ + c0;
    const float* Qb = Q + (size_t)b * D_ * LQ_ + q0;
    const int tid = threadIdx.x;
    const int tx = tid & 15;     // -> q, strided 16 (coalesced S writes)
    const int ty = tid >> 4;     // -> c, 4 consecutive (float4 LDS read)
    float acc[4][8];
    #pragma unroll
    for (int i = 0; i < 4; ++i)
        #pragma unroll
        for (int j = 0; j < 8; ++j) acc[i][j] = 0.f;

    for (int d0 = 0; d0 < D_; d0 += 32) {
        __syncthreads();
        {
            int lc = tid & 63, kr = tid >> 6;       // kr 0..3
            #pragma unroll
            for (int r = 0; r < 8; ++r) {
                int k = r * 4 + kr;
                As[k][lc] = Cb[(size_t)(d0 + k) * LC_ + lc] * w4mlu[d0 + k];
            }
            int lq = tid & 127, kr2 = tid >> 7;     // kr2 0..1
            #pragma unroll
            for (int r = 0; r < 16; ++r) {
                int k = r * 2 + kr2;
                Bs[k][lq] = Qb[(size_t)(d0 + k) * LQ_ + lq];
            }
        }
        __syncthreads();
        #pragma unroll
        for (int k = 0; k < 32; ++k) {
            float4 av = *(const float4*)&As[k][ty * 4];
            float a[4] = {av.x, av.y, av.z, av.w};
            float bv[8];
            #pragma unroll
            for (int j = 0; j < 8; ++j) bv[j] = Bs[k][tx + j * 16];
            #pragma unroll
            for (int i = 0; i < 4; ++i)
                #pragma unroll
                for (int j = 0; j < 8; ++j) acc[i][j] += a[i] * bv[j];
        }
    }
    #pragma unroll
    for (int i = 0; i < 4; ++i) {
        int c = c0 + ty * 4 + i;
        float s0 = sub0[b * LC_ + c];
        float* Srow = S + ((size_t)b * LC_ + c) * LQ_ + q0;
        #pragma unroll
        for (int j = 0; j < 8; ++j) {
            int q = tx + j * 16;
            Srow[q] = acc[i][j] + s0 + sub1[b * LQ_ + q0 + q];
        }
    }
}

// ---------------------------------------------------------------------------
// K3: row softmax stats (over q). one block per (b,c) row.
// ---------------------------------------------------------------------------
__global__ __launch_bounds__(256) void k_rowstat(
        const float* __restrict__ S, const int* __restrict__ Qmask,
        float* __restrict__ rowM, float* __restrict__ rowR) {
    int row = blockIdx.x;               // b*LC_ + c
    int b = row >> 11;
    const float* Sr = S + (size_t)row * LQ_;
    int t = threadIdx.x;
    float x0 = Sr[t]       + (Qmask[b * LQ_ + t]       ? 0.f : NEG_);
    float x1 = Sr[t + 256] + (Qmask[b * LQ_ + t + 256] ? 0.f : NEG_);
    float m = fmaxf(x0, x1);
    #pragma unroll
    for (int o = 32; o > 0; o >>= 1) m = fmaxf(m, __shfl_xor(m, o));
    __shared__ float sm[4], sz[4];
    int wv = t >> 6;
    if ((t & 63) == 0) sm[wv] = m;
    __syncthreads();
    m = fmaxf(fmaxf(sm[0], sm[1]), fmaxf(sm[2], sm[3]));
    float z = __expf(x0 - m) + __expf(x1 - m);
    #pragma unroll
    for (int o = 32; o > 0; o >>= 1) z += __shfl_xor(z, o);
    if ((t & 63) == 0) sz[wv] = z;
    __syncthreads();
    if (t == 0) {
        z = sz[0] + sz[1] + sz[2] + sz[3];
        rowM[row] = m;
        rowR[row] = 1.f / z;
    }
}

// ---------------------------------------------------------------------------
// K4: partial column stats (softmax over c), c split into 4 chunks of 512.
// grid (LQ/64, 4, B), block 256 = 64 q-lanes x 4 c-strides
// ---------------------------------------------------------------------------
__global__ __launch_bounds__(256) void k_colstat_part(
        const float* __restrict__ S, const int* __restrict__ Cmask,
        float* __restrict__ colMp, float* __restrict__ colZp) {
    int b = blockIdx.z, cc = blockIdx.y, q0 = blockIdx.x * 64;
    int t = threadIdx.x;
    int qi = t & 63, ci = t >> 6;
    const float* Sb = S + (size_t)b * LC_ * LQ_ + q0 + qi;
    const int* cm = Cmask + b * LC_;
    float m = -INFINITY, z = 0.f;
    int cbase = cc * 512;
    for (int c = cbase + ci; c < cbase + 512; c += 4) {
        float x = Sb[(size_t)c * LQ_] + (cm[c] ? 0.f : NEG_);
        if (x <= m) { z += __expf(x - m); }
        else        { z = z * __expf(m - x) + 1.f; m = x; }
    }
    __shared__ float sm[4][64], sz[4][64];
    sm[ci][qi] = m; sz[ci][qi] = z;
    __syncthreads();
    if (t < 64) {
        float M = sm[0][qi], Z = sz[0][qi];
        #pragma unroll
        for (int i = 1; i < 4; ++i) {
            float m2 = sm[i][qi], z2 = sz[i][qi];
            float Mn = fmaxf(M, m2);
            Z = Z * __expf(M - Mn) + z2 * __expf(m2 - Mn);
            M = Mn;
        }
        size_t o = ((size_t)cc * B_ + b) * LQ_ + q0 + qi;
        colMp[o] = M; colZp[o] = Z;
    }
}

__global__ __launch_bounds__(256) void k_colcomb(
        const float* __restrict__ colMp, const float* __restrict__ colZp,
        float* __restrict__ colM, float* __restrict__ colR) {
    int i = blockIdx.x * 256 + threadIdx.x;   // b*LQ + q
    float M = -INFINITY, Z = 0.f;
    #pragma unroll
    for (int cc = 0; cc < 4; ++cc) {
        float m2 = colMp[(size_t)cc * (B_ * LQ_) + i];
        float z2 = colZp[(size_t)cc * (B_ * LQ_) + i];
        float Mn = fmaxf(M, m2);
        Z = Z * __expf(M - Mn) + z2 * __expf(m2 - Mn);
        M = Mn;
    }
    colM[i] = M; colR[i] = 1.f / Z;
}

// ---------------------------------------------------------------------------
// K5: T[b,q,d] = colR[q] * sum_c exp(S[b,c,q]-colM[q]) * C[b,d,c]   (cm-masked)
// tile 64q x 64d, K=c loop BK=32. grid (2, LQ/64, B) = 256 blocks
// ---------------------------------------------------------------------------
__global__ __launch_bounds__(256) void k_tgemm(
        const float* __restrict__ S, const float* __restrict__ C,
        const int* __restrict__ Cmask,
        const float* __restrict__ colM, const float* __restrict__ colR,
        float* __restrict__ Tm) {
    __shared__ float Es[32][64];    // [kc][q]
    __shared__ float Cs[32][65];    // [kc][d] padded
    __shared__ float cMs[64], cRs[64];
    const int b  = blockIdx.z;
    const int q0 = blockIdx.y * 64;
    const int d0 = blockIdx.x * 64;
    const int tid = threadIdx.x;
    const int tx = tid & 15;    // -> d strided 16 (coalesced T writes)
    const int ty = tid >> 4;    // -> q, 4 consecutive
    if (tid < 64) { cMs[tid] = colM[b * LQ_ + q0 + tid]; cRs[tid] = colR[b * LQ_ + q0 + tid]; }
    const float* Sb = S + (size_t)b * LC_ * LQ_ + q0;
    const float* Cb = C + (size_t)b * D_ * LC_;
    const int* cm = Cmask + b * LC_;
    float acc[4][4];
    #pragma unroll
    for (int i = 0; i < 4; ++i)
        #pragma unroll
        for (int j = 0; j < 4; ++j) acc[i][j] = 0.f;

    for (int c0 = 0; c0 < LC_; c0 += 32) {
        __syncthreads();
        {
            int lq = tid & 63, kr = tid >> 6;
            #pragma unroll
            for (int r = 0; r < 8; ++r) {
                int k = r * 4 + kr;
                float x = Sb[(size_t)(c0 + k) * LQ_ + lq];
                Es[k][lq] = cm[c0 + k] ? __expf(x - cMs[lq]) : 0.f;
            }
            int lk = tid & 31, dr = tid >> 5;
            #pragma unroll
            for (int r = 0; r < 8; ++r) {
                int d = r * 8 + dr;
                Cs[lk][d] = Cb[(size_t)(d0 + d) * LC_ + c0 + lk];
            }
        }
        __syncthreads();
        #pragma unroll
        for (int k = 0; k < 32; ++k) {
            float4 ev = *(const float4*)&Es[k][ty * 4];
            float e[4] = {ev.x, ev.y, ev.z, ev.w};
            float cv[4];
            #pragma unroll
            for (int j = 0; j < 4; ++j) cv[j] = Cs[k][tx + j * 16];
            #pragma unroll
            for (int i = 0; i < 4; ++i)
                #pragma unroll
                for (int j = 0; j < 4; ++j) acc[i][j] += e[i] * cv[j];
        }
    }
    #pragma unroll
    for (int i = 0; i < 4; ++i) {
        int q = ty * 4 + i;
        float r = cRs[q];
        float* Tp = Tm + ((size_t)b * LQ_ + q0 + q) * D_ + d0;
        #pragma unroll
        for (int j = 0; j < 4; ++j) Tp[tx + j * 16] = acc[i][j] * r;
    }
}

// ---------------------------------------------------------------------------
// K6: final. per (b, c-tile 64): A = S1 @ Qt, Bm = S1 @ T over K=q=512,
// then out = [Ct, A, Ct*A, Ct*Bm] with out[b,f,c] layout.
// grid (LC/64, B) = 512 blocks, 256 thr, micro 4c(strided) x 8d(consec)
// ---------------------------------------------------------------------------
__global__ __launch_bounds__(256) void k_final(
        const float* __restrict__ S, const float* __restrict__ Q,
        const float* __restrict__ Tm, const float* __restrict__ C,
        const int* __restrict__ Qmask,
        const float* __restrict__ rowM, const float* __restrict__ rowR,
        float* __restrict__ out) {
    __shared__ float smem[2080 + 4224 + 4224];     // Ss | Qs | Ts ; reused for Cts
    float (*Ss)[65]   = (float (*)[65])smem;            // [kq][c]
    float (*Qs)[132]  = (float (*)[132])(smem + 2080);  // [kq][d] (132: 16B-aligned rows)
    float (*Ts)[132]  = (float (*)[132])(smem + 2080 + 4224);
    float (*Cts)[65]  = (float (*)[65])smem;            // [d][c], reuse after K loop
    __shared__ float rMs[64], rRs[64];
    const int b  = blockIdx.y;
    const int c0 = blockIdx.x * 64;
    const int tid = threadIdx.x;
    const int tx = tid & 15;    // -> c strided 16 (coalesced out writes)
    const int ty = tid >> 4;    // -> d, 8 consecutive (float4 LDS reads)
    if (tid < 64) { rMs[tid] = rowM[b * LC_ + c0 + tid]; rRs[tid] = rowR[b * LC_ + c0 + tid]; }
    const float* Sb = S + (size_t)b * LC_ * LQ_;
    const float* Qb = Q + (size_t)b * D_ * LQ_;
    const float* Tb = Tm + (size_t)b * LQ_ * D_;
    const float* Cb = C + (size_t)b * D_ * LC_;
    const int* qm = Qmask + b * LQ_;
    float accA[4][8], accB[4][8];
    #pragma unroll
    for (int i = 0; i < 4; ++i)
        #pragma unroll
        for (int j = 0; j < 8; ++j) { accA[i][j] = 0.f; accB[i][j] = 0.f; }

    for (int p0 = 0; p0 < LQ_; p0 += 32) {
        __syncthreads();
        {
            int lq = tid & 31, cr = tid >> 5;   // cr 0..7
            #pragma unroll
            for (int r = 0; r < 8; ++r) {
                int c = r * 8 + cr;
                float x = Sb[(size_t)(c0 + c) * LQ_ + p0 + lq];
                x += qm[p0 + lq] ? 0.f : NEG_;
                Ss[lq][c] = __expf(x - rMs[c]);
            }
            #pragma unroll
            for (int r = 0; r < 16; ++r) {
                int d = r * 8 + cr;
                Qs[lq][d] = Qb[(size_t)d * LQ_ + p0 + lq];
            }
            int ld = tid & 127, qr = tid >> 7;
            #pragma unroll
            for (int r = 0; r < 16; ++r) {
                int q = r * 2 + qr;
                Ts[q][ld] = Tb[(size_t)(p0 + q) * D_ + ld];
            }
        }
        __syncthreads();
        #pragma unroll
        for (int k = 0; k < 32; ++k) {
            float s[4];
            #pragma unroll
            for (int i = 0; i < 4; ++i) s[i] = Ss[k][tx + i * 16];
            float4 qv0 = *(const float4*)&Qs[k][ty * 8];
            float4 qv1 = *(const float4*)&Qs[k][ty * 8 + 4];
            float4 tv0 = *(const float4*)&Ts[k][ty * 8];
            float4 tv1 = *(const float4*)&Ts[k][ty * 8 + 4];
            float qv[8] = {qv0.x, qv0.y, qv0.z, qv0.w, qv1.x, qv1.y, qv1.z, qv1.w};
            float tv[8] = {tv0.x, tv0.y, tv0.z, tv0.w, tv1.x, tv1.y, tv1.z, tv1.w};
            #pragma unroll
            for (int i = 0; i < 4; ++i)
                #pragma unroll
                for (int j = 0; j < 8; ++j) {
                    accA[i][j] += s[i] * qv[j];
                    accB[i][j] += s[i] * tv[j];
                }
        }
    }
    __syncthreads();
    {   // stage Ct tile [128][64] into reused LDS
        int lc = tid & 63, dr = tid >> 6;
        #pragma unroll
        for (int r = 0; r < 32; ++r) {
            int d = r * 4 + dr;
            Cts[d][lc] = Cb[(size_t)d * LC_ + c0 + lc];
        }
    }
    __syncthreads();
    #pragma unroll
    for (int i = 0; i < 4; ++i) {
        int cl = tx + i * 16;
        int c = c0 + cl;
        float rr = rRs[cl];
        #pragma unroll
        for (int j = 0; j < 8; ++j) {
            int d = ty * 8 + j;
            float ct = Cts[d][cl];
            float a  = accA[i][j] * rr;
            float bm = accB[i][j] * rr;
            size_t base = ((size_t)b * (4 * D_) + d) * LC_ + c;
            out[base] = ct;
            out[base + (size_t)D_ * LC_] = a;
            out[base + (size_t)2 * D_ * LC_] = ct * a;
            out[base + (size_t)3 * D_ * LC_] = ct * bm;
        }
    }
}

// ---------------------------------------------------------------------------
extern "C" void kernel_launch(void* const* d_in, const int* in_sizes, int n_in,
                              void* d_out, int out_size, void* d_ws, size_t ws_size,
                              hipStream_t stream) {
    (void)in_sizes; (void)n_in; (void)out_size; (void)ws_size;
    const float* C     = (const float*)d_in[0];
    const float* Q     = (const float*)d_in[1];
    const int*   Cmask = (const int*)d_in[2];
    const int*   Qmask = (const int*)d_in[3];
    const float* w4C   = (const float*)d_in[4];
    const float* w4Q   = (const float*)d_in[5];
    const float* w4mlu = (const float*)d_in[6];
    const float* bias  = (const float*)d_in[7];
    float* out = (float*)d_out;

    // workspace layout (floats); total ~72 MB
    float* ws    = (float*)d_ws;
    float* S     = ws;                                   // 16*2048*512
    float* Tmat  = S + (size_t)B_ * LC_ * LQ_;           // 16*512*128
    float* sub0  = Tmat + (size_t)B_ * LQ_ * D_;         // 16*2048
    float* sub1  = sub0 + B_ * LC_;                      // 16*512
    float* rowM  = sub1 + B_ * LQ_;                      // 16*2048
    float* rowR  = rowM + B_ * LC_;                      // 16*2048
    float* colM  = rowR + B_ * LC_;                      // 16*512
    float* colR  = colM + B_ * LQ_;                      // 16*512
    float* colMp = colR + B_ * LQ_;                      // 4*16*512
    float* colZp = colMp + 4 * B_ * LQ_;                 // 4*16*512

    k_subs<<<B_ * (LC_ / 256) + B_ * (LQ_ / 256), 256, 0, stream>>>(
        C, Q, w4C, w4Q, bias, sub0, sub1);
    k_sgemm<<<dim3(LQ_ / 128, LC_ / 64, B_), 256, 0, stream>>>(
        C, Q, w4mlu, sub0, sub1, S);
    k_rowstat<<<B_ * LC_, 256, 0, stream>>>(S, Qmask, rowM, rowR);
    k_colstat_part<<<dim3(LQ_ / 64, 4, B_), 256, 0, stream>>>(S, Cmask, colMp, colZp);
    k_colcomb<<<B_ * LQ_ / 256, 256, 0, stream>>>(colMp, colZp, colM, colR);
    k_tgemm<<<dim3(D_ / 64, LQ_ / 64, B_), 256, 0, stream>>>(
        S, C, Cmask, colM, colR, Tmat);
    k_final<<<dim3(LC_ / 64, B_), 256, 0, stream>>>(
        S, Q, Tmat, C, Qmask, rowM, rowR, out);
}

// Round 2
// 433.840 us; speedup vs baseline: 1.5403x; 1.5403x over previous
//
#include <hip/hip_runtime.h>
#include <math.h>

#define B_ 16
#define D_ 128
#define LC_ 2048
#define LQ_ 512
#define NEG_ (-1e30f)

// ---------------------------------------------------------------------------
// K1: sub0[b,c] = sum_d C[b,d,c]*w4C[d];  sub1[b,q] = sum_d Q[b,d,q]*w4Q[d] + bias
// ---------------------------------------------------------------------------
__global__ __launch_bounds__(256) void k_subs(
        const float* __restrict__ C, const float* __restrict__ Q,
        const float* __restrict__ w4C, const float* __restrict__ w4Q,
        const float* __restrict__ bias,
        float* __restrict__ sub0, float* __restrict__ sub1) {
    int bid = blockIdx.x;
    const int nb0 = B_ * (LC_ / 256);   // 128
    if (bid < nb0) {
        int b = bid / (LC_ / 256);
        int c = (bid % (LC_ / 256)) * 256 + threadIdx.x;
        const float* Cb = C + (size_t)b * D_ * LC_;
        float acc = 0.f;
        #pragma unroll 8
        for (int d = 0; d < D_; ++d) acc += Cb[(size_t)d * LC_ + c] * w4C[d];
        sub0[b * LC_ + c] = acc;
    } else {
        int id = bid - nb0;
        int b = id / (LQ_ / 256);
        int q = (id % (LQ_ / 256)) * 256 + threadIdx.x;
        const float* Qb = Q + (size_t)b * D_ * LQ_;
        float acc = bias[0];
        #pragma unroll 8
        for (int d = 0; d < D_; ++d) acc += Qb[(size_t)d * LQ_ + q] * w4Q[d];
        sub1[b * LQ_ + q] = acc;
    }
}

// ---------------------------------------------------------------------------
// K2: S[b,c,q] = sum_d (C[b,d,c]*w4mlu[d]) * Q[b,d,q] + sub0[c] + sub1[q]
// ---------------------------------------------------------------------------
__global__ __launch_bounds__(256) void k_sgemm(
        const float* __restrict__ C, const float* __restrict__ Q,
        const float* __restrict__ w4mlu,
        const float* __restrict__ sub0, const float* __restrict__ sub1,
        float* __restrict__ S) {
    __shared__ float As[32][64];    // [k][c]
    __shared__ float Bs[32][128];   // [k][q]
    const int b  = blockIdx.z;
    const int c0 = blockIdx.y * 64;
    const int q0 = blockIdx.x * 128;
    const float* Cb = C + (size_t)b * D_ * LC_ + c0;
    const float* Qb = Q + (size_t)b * D_ * LQ_ + q0;
    const int tid = threadIdx.x;
    const int tx = tid & 15;     // -> q, strided 16 (coalesced S writes)
    const int ty = tid >> 4;     // -> c, 4 consecutive (float4 LDS read)
    float acc[4][8];
    #pragma unroll
    for (int i = 0; i < 4; ++i)
        #pragma unroll
        for (int j = 0; j < 8; ++j) acc[i][j] = 0.f;

    for (int d0 = 0; d0 < D_; d0 += 32) {
        __syncthreads();
        {
            int lc = tid & 63, kr = tid >> 6;       // kr 0..3
            #pragma unroll
            for (int r = 0; r < 8; ++r) {
                int k = r * 4 + kr;
                As[k][lc] = Cb[(size_t)(d0 + k) * LC_ + lc] * w4mlu[d0 + k];
            }
            int lq = tid & 127, kr2 = tid >> 7;     // kr2 0..1
            #pragma unroll
            for (int r = 0; r < 16; ++r) {
                int k = r * 2 + kr2;
                Bs[k][lq] = Qb[(size_t)(d0 + k) * LQ_ + lq];
            }
        }
        __syncthreads();
        #pragma unroll
        for (int k = 0; k < 32; ++k) {
            float4 av = *(const float4*)&As[k][ty * 4];
            float a[4] = {av.x, av.y, av.z, av.w};
            float bv[8];
            #pragma unroll
            for (int j = 0; j < 8; ++j) bv[j] = Bs[k][tx + j * 16];
            #pragma unroll
            for (int i = 0; i < 4; ++i)
                #pragma unroll
                for (int j = 0; j < 8; ++j) acc[i][j] += a[i] * bv[j];
        }
    }
    #pragma unroll
    for (int i = 0; i < 4; ++i) {
        int c = c0 + ty * 4 + i;
        float s0 = sub0[b * LC_ + c];
        float* Srow = S + ((size_t)b * LC_ + c) * LQ_ + q0;
        #pragma unroll
        for (int j = 0; j < 8; ++j) {
            int q = tx + j * 16;
            Srow[q] = acc[i][j] + s0 + sub1[b * LQ_ + q0 + q];
        }
    }
}

// ---------------------------------------------------------------------------
// K3: row softmax stats (over q). one block per (b,c) row.
// ---------------------------------------------------------------------------
__global__ __launch_bounds__(256) void k_rowstat(
        const float* __restrict__ S, const int* __restrict__ Qmask,
        float* __restrict__ rowM, float* __restrict__ rowR) {
    int row = blockIdx.x;               // b*LC_ + c
    int b = row >> 11;
    const float* Sr = S + (size_t)row * LQ_;
    int t = threadIdx.x;
    float x0 = Sr[t]       + (Qmask[b * LQ_ + t]       ? 0.f : NEG_);
    float x1 = Sr[t + 256] + (Qmask[b * LQ_ + t + 256] ? 0.f : NEG_);
    float m = fmaxf(x0, x1);
    #pragma unroll
    for (int o = 32; o > 0; o >>= 1) m = fmaxf(m, __shfl_xor(m, o));
    __shared__ float sm[4], sz[4];
    int wv = t >> 6;
    if ((t & 63) == 0) sm[wv] = m;
    __syncthreads();
    m = fmaxf(fmaxf(sm[0], sm[1]), fmaxf(sm[2], sm[3]));
    float z = __expf(x0 - m) + __expf(x1 - m);
    #pragma unroll
    for (int o = 32; o > 0; o >>= 1) z += __shfl_xor(z, o);
    if ((t & 63) == 0) sz[wv] = z;
    __syncthreads();
    if (t == 0) {
        z = sz[0] + sz[1] + sz[2] + sz[3];
        rowM[row] = m;
        rowR[row] = 1.f / z;
    }
}

// ---------------------------------------------------------------------------
// K4: partial column stats (softmax over c), c split into 4 chunks of 512.
// ---------------------------------------------------------------------------
__global__ __launch_bounds__(256) void k_colstat_part(
        const float* __restrict__ S, const int* __restrict__ Cmask,
        float* __restrict__ colMp, float* __restrict__ colZp) {
    int b = blockIdx.z, cc = blockIdx.y, q0 = blockIdx.x * 64;
    int t = threadIdx.x;
    int qi = t & 63, ci = t >> 6;
    const float* Sb = S + (size_t)b * LC_ * LQ_ + q0 + qi;
    const int* cm = Cmask + b * LC_;
    float m = -INFINITY, z = 0.f;
    int cbase = cc * 512;
    for (int c = cbase + ci; c < cbase + 512; c += 4) {
        float x = Sb[(size_t)c * LQ_] + (cm[c] ? 0.f : NEG_);
        if (x <= m) { z += __expf(x - m); }
        else        { z = z * __expf(m - x) + 1.f; m = x; }
    }
    __shared__ float sm[4][64], sz[4][64];
    sm[ci][qi] = m; sz[ci][qi] = z;
    __syncthreads();
    if (t < 64) {
        float M = sm[0][qi], Z = sz[0][qi];
        #pragma unroll
        for (int i = 1; i < 4; ++i) {
            float m2 = sm[i][qi], z2 = sz[i][qi];
            float Mn = fmaxf(M, m2);
            Z = Z * __expf(M - Mn) + z2 * __expf(m2 - Mn);
            M = Mn;
        }
        size_t o = ((size_t)cc * B_ + b) * LQ_ + q0 + qi;
        colMp[o] = M; colZp[o] = Z;
    }
}

__global__ __launch_bounds__(256) void k_colcomb(
        const float* __restrict__ colMp, const float* __restrict__ colZp,
        float* __restrict__ colM, float* __restrict__ colR) {
    int i = blockIdx.x * 256 + threadIdx.x;   // b*LQ + q
    float M = -INFINITY, Z = 0.f;
    #pragma unroll
    for (int cc = 0; cc < 4; ++cc) {
        float m2 = colMp[(size_t)cc * (B_ * LQ_) + i];
        float z2 = colZp[(size_t)cc * (B_ * LQ_) + i];
        float Mn = fmaxf(M, m2);
        Z = Z * __expf(M - Mn) + z2 * __expf(m2 - Mn);
        M = Mn;
    }
    colM[i] = M; colR[i] = 1.f / Z;
}

// ---------------------------------------------------------------------------
// K5a: split-K partial of T: Tpart[sp,b,q,d] = sum_{c in chunk sp}
//      exp(S[b,c,q]-colM[q]) * C[b,d,c]   (cm-masked, NO colR yet)
// tile 64q x 128d, chunk = LC/nsplit. grid (LQ/64, nsplit, B)
// ---------------------------------------------------------------------------
__global__ __launch_bounds__(256) void k_tgemm_part(
        const float* __restrict__ S, const float* __restrict__ C,
        const int* __restrict__ Cmask, const float* __restrict__ colM,
        float* __restrict__ Tpart, int chunk) {
    __shared__ float Es[32][64];     // [kc][q]
    __shared__ float Cs[32][133];    // [kc][d]  (133 % 32 = 5, coprime -> conflict-free col writes)
    __shared__ float cMs[64];
    const int b  = blockIdx.z;
    const int sp = blockIdx.y;
    const int q0 = blockIdx.x * 64;
    const int tid = threadIdx.x;
    const int tx = tid & 15;    // -> d strided 16
    const int ty = tid >> 4;    // -> q, 4 consecutive
    if (tid < 64) cMs[tid] = colM[b * LQ_ + q0 + tid];
    const float* Sb = S + (size_t)b * LC_ * LQ_ + q0;
    const float* Cb = C + (size_t)b * D_ * LC_;
    const int* cm = Cmask + b * LC_;
    float acc[4][8];
    #pragma unroll
    for (int i = 0; i < 4; ++i)
        #pragma unroll
        for (int j = 0; j < 8; ++j) acc[i][j] = 0.f;

    const int cbeg = sp * chunk;
    for (int c0 = cbeg; c0 < cbeg + chunk; c0 += 32) {
        __syncthreads();
        {
            int lq = tid & 63, kr = tid >> 6;     // kr 0..3
            #pragma unroll
            for (int r = 0; r < 8; ++r) {
                int k = r * 4 + kr;
                float x = Sb[(size_t)(c0 + k) * LQ_ + lq];
                Es[k][lq] = cm[c0 + k] ? __expf(x - cMs[lq]) : 0.f;
            }
            int lk = tid & 31, dr = tid >> 5;     // dr 0..7
            #pragma unroll
            for (int r = 0; r < 16; ++r) {
                int d = r * 8 + dr;
                Cs[lk][d] = Cb[(size_t)d * LC_ + c0 + lk];
            }
        }
        __syncthreads();
        #pragma unroll
        for (int k = 0; k < 32; ++k) {
            float4 ev = *(const float4*)&Es[k][ty * 4];
            float e[4] = {ev.x, ev.y, ev.z, ev.w};
            float cv[8];
            #pragma unroll
            for (int j = 0; j < 8; ++j) cv[j] = Cs[k][tx + j * 16];
            #pragma unroll
            for (int i = 0; i < 4; ++i)
                #pragma unroll
                for (int j = 0; j < 8; ++j) acc[i][j] += e[i] * cv[j];
        }
    }
    float* Tp = Tpart + (((size_t)sp * B_ + b) * LQ_ + q0) * D_;
    #pragma unroll
    for (int i = 0; i < 4; ++i) {
        int q = ty * 4 + i;
        #pragma unroll
        for (int j = 0; j < 8; ++j)
            Tp[(size_t)q * D_ + tx + j * 16] = acc[i][j];
    }
}

// K5b: T[b,q,d] = colR[b,q] * sum_sp Tpart[sp,b,q,d]   (float4-vectorized)
__global__ __launch_bounds__(256) void k_treduce(
        const float* __restrict__ Tpart, const float* __restrict__ colR,
        float* __restrict__ Tm, int nsplit) {
    int idx = blockIdx.x * 256 + threadIdx.x;        // float4 index
    const size_t stride4 = (size_t)B_ * LQ_ * D_ / 4;
    const float4* Tp = (const float4*)Tpart;
    float4 s = Tp[idx];
    for (int sp = 1; sp < nsplit; ++sp) {
        float4 v = Tp[(size_t)sp * stride4 + idx];
        s.x += v.x; s.y += v.y; s.z += v.z; s.w += v.w;
    }
    float r = colR[(idx * 4) / D_];
    float4 o = {s.x * r, s.y * r, s.z * r, s.w * r};
    ((float4*)Tm)[idx] = o;
}

// ---------------------------------------------------------------------------
// K6: final. per (b, c-tile 64): A = S1 @ Qt, Bm = S1 @ T over K=q=512,
// then out = [Ct, A, Ct*A, Ct*Bm] with out[b,f,c] layout.
// ---------------------------------------------------------------------------
__global__ __launch_bounds__(256) void k_final(
        const float* __restrict__ S, const float* __restrict__ Q,
        const float* __restrict__ Tm, const float* __restrict__ C,
        const int* __restrict__ Qmask,
        const float* __restrict__ rowM, const float* __restrict__ rowR,
        float* __restrict__ out) {
    __shared__ float smem[2080 + 4224 + 4224];     // Ss | Qs | Ts ; reused for Cts
    float (*Ss)[65]   = (float (*)[65])smem;            // [kq][c]
    float (*Qs)[132]  = (float (*)[132])(smem + 2080);  // [kq][d]
    float (*Ts)[132]  = (float (*)[132])(smem + 2080 + 4224);
    float (*Cts)[65]  = (float (*)[65])smem;            // [d][c], reuse after K loop
    __shared__ float rMs[64], rRs[64];
    const int b  = blockIdx.y;
    const int c0 = blockIdx.x * 64;
    const int tid = threadIdx.x;
    const int tx = tid & 15;    // -> c strided 16 (coalesced out writes)
    const int ty = tid >> 4;    // -> d, 8 consecutive (float4 LDS reads)
    if (tid < 64) { rMs[tid] = rowM[b * LC_ + c0 + tid]; rRs[tid] = rowR[b * LC_ + c0 + tid]; }
    const float* Sb = S + (size_t)b * LC_ * LQ_;
    const float* Qb = Q + (size_t)b * D_ * LQ_;
    const float* Tb = Tm + (size_t)b * LQ_ * D_;
    const float* Cb = C + (size_t)b * D_ * LC_;
    const int* qm = Qmask + b * LQ_;
    float accA[4][8], accB[4][8];
    #pragma unroll
    for (int i = 0; i < 4; ++i)
        #pragma unroll
        for (int j = 0; j < 8; ++j) { accA[i][j] = 0.f; accB[i][j] = 0.f; }

    for (int p0 = 0; p0 < LQ_; p0 += 32) {
        __syncthreads();
        {
            int lq = tid & 31, cr = tid >> 5;   // cr 0..7
            #pragma unroll
            for (int r = 0; r < 8; ++r) {
                int c = r * 8 + cr;
                float x = Sb[(size_t)(c0 + c) * LQ_ + p0 + lq];
                x += qm[p0 + lq] ? 0.f : NEG_;
                Ss[lq][c] = __expf(x - rMs[c]);
            }
            #pragma unroll
            for (int r = 0; r < 16; ++r) {
                int d = r * 8 + cr;
                Qs[lq][d] = Qb[(size_t)d * LQ_ + p0 + lq];
            }
            int ld = tid & 127, qr = tid >> 7;
            #pragma unroll
            for (int r = 0; r < 16; ++r) {
                int q = r * 2 + qr;
                Ts[q][ld] = Tb[(size_t)(p0 + q) * D_ + ld];
            }
        }
        __syncthreads();
        #pragma unroll
        for (int k = 0; k < 32; ++k) {
            float s[4];
            #pragma unroll
            for (int i = 0; i < 4; ++i) s[i] = Ss[k][tx + i * 16];
            float4 qv0 = *(const float4*)&Qs[k][ty * 8];
            float4 qv1 = *(const float4*)&Qs[k][ty * 8 + 4];
            float4 tv0 = *(const float4*)&Ts[k][ty * 8];
            float4 tv1 = *(const float4*)&Ts[k][ty * 8 + 4];
            float qv[8] = {qv0.x, qv0.y, qv0.z, qv0.w, qv1.x, qv1.y, qv1.z, qv1.w};
            float tv[8] = {tv0.x, tv0.y, tv0.z, tv0.w, tv1.x, tv1.y, tv1.z, tv1.w};
            #pragma unroll
            for (int i = 0; i < 4; ++i)
                #pragma unroll
                for (int j = 0; j < 8; ++j) {
                    accA[i][j] += s[i] * qv[j];
                    accB[i][j] += s[i] * tv[j];
                }
        }
    }
    __syncthreads();
    {   // stage Ct tile [128][64] into reused LDS
        int lc = tid & 63, dr = tid >> 6;
        #pragma unroll
        for (int r = 0; r < 32; ++r) {
            int d = r * 4 + dr;
            Cts[d][lc] = Cb[(size_t)d * LC_ + c0 + lc];
        }
    }
    __syncthreads();
    #pragma unroll
    for (int i = 0; i < 4; ++i) {
        int cl = tx + i * 16;
        int c = c0 + cl;
        float rr = rRs[cl];
        #pragma unroll
        for (int j = 0; j < 8; ++j) {
            int d = ty * 8 + j;
            float ct = Cts[d][cl];
            float a  = accA[i][j] * rr;
            float bm = accB[i][j] * rr;
            size_t base = ((size_t)b * (4 * D_) + d) * LC_ + c;
            out[base] = ct;
            out[base + (size_t)D_ * LC_] = a;
            out[base + (size_t)2 * D_ * LC_] = ct * a;
            out[base + (size_t)3 * D_ * LC_] = ct * bm;
        }
    }
}

// ---------------------------------------------------------------------------
extern "C" void kernel_launch(void* const* d_in, const int* in_sizes, int n_in,
                              void* d_out, int out_size, void* d_ws, size_t ws_size,
                              hipStream_t stream) {
    (void)in_sizes; (void)n_in; (void)out_size;
    const float* C     = (const float*)d_in[0];
    const float* Q     = (const float*)d_in[1];
    const int*   Cmask = (const int*)d_in[2];
    const int*   Qmask = (const int*)d_in[3];
    const float* w4C   = (const float*)d_in[4];
    const float* w4Q   = (const float*)d_in[5];
    const float* w4mlu = (const float*)d_in[6];
    const float* bias  = (const float*)d_in[7];
    float* out = (float*)d_out;

    // workspace layout (floats)
    float* ws    = (float*)d_ws;
    float* S     = ws;                                   // 16*2048*512   (67 MB)
    float* Tmat  = S + (size_t)B_ * LC_ * LQ_;           // 16*512*128    (4 MB)
    float* sub0  = Tmat + (size_t)B_ * LQ_ * D_;
    float* sub1  = sub0 + B_ * LC_;
    float* rowM  = sub1 + B_ * LQ_;
    float* rowR  = rowM + B_ * LC_;
    float* colM  = rowR + B_ * LC_;
    float* colR  = colM + B_ * LQ_;
    float* colMp = colR + B_ * LQ_;                      // 4*16*512
    float* colZp = colMp + 4 * B_ * LQ_;                 // 4*16*512
    float* Tpart = colZp + 4 * B_ * LQ_;                 // nsplit*16*512*128

    // pick the largest split-K factor that fits the workspace
    size_t base_floats = (size_t)(Tpart - ws);
    size_t avail = ws_size / 4 > base_floats ? ws_size / 4 - base_floats : 0;
    int nsplit = 8;
    while (nsplit > 1 && (size_t)nsplit * B_ * LQ_ * D_ > avail) nsplit >>= 1;
    if ((size_t)nsplit * B_ * LQ_ * D_ > avail) { Tpart = Tmat; nsplit = 1; }  // degenerate fallback
    int chunk = LC_ / nsplit;

    k_subs<<<B_ * (LC_ / 256) + B_ * (LQ_ / 256), 256, 0, stream>>>(
        C, Q, w4C, w4Q, bias, sub0, sub1);
    k_sgemm<<<dim3(LQ_ / 128, LC_ / 64, B_), 256, 0, stream>>>(
        C, Q, w4mlu, sub0, sub1, S);
    k_rowstat<<<B_ * LC_, 256, 0, stream>>>(S, Qmask, rowM, rowR);
    k_colstat_part<<<dim3(LQ_ / 64, 4, B_), 256, 0, stream>>>(S, Cmask, colMp, colZp);
    k_colcomb<<<B_ * LQ_ / 256, 256, 0, stream>>>(colMp, colZp, colM, colR);
    k_tgemm_part<<<dim3(LQ_ / 64, nsplit, B_), 256, 0, stream>>>(
        S, C, Cmask, colM, Tpart, chunk);
    k_treduce<<<B_ * LQ_ * D_ / 4 / 256, 256, 0, stream>>>(Tpart, colR, Tmat, nsplit);
    k_final<<<dim3(LC_ / 64, B_), 256, 0, stream>>>(
        S, Q, Tmat, C, Qmask, rowM, rowR, out);
}

// Round 4
// 194.065 us; speedup vs baseline: 3.4434x; 2.2355x over previous
//
#include <hip/hip_runtime.h>
#include <math.h>

#define B_ 16
#define D_ 128
#define LC_ 2048
#define LQ_ 512
#define SHIFT_ 12.0f

typedef unsigned short ushort_t;
typedef short short8 __attribute__((ext_vector_type(8)));
typedef float f32x4 __attribute__((ext_vector_type(4)));

__device__ __forceinline__ ushort_t f2bf(float f) {
    union { float f; unsigned int u; } v; v.f = f;
    unsigned int r = (v.u + 0x7FFFu + ((v.u >> 16) & 1u)) >> 16;
    return (ushort_t)r;
}
__device__ __forceinline__ float bf2f(ushort_t h) {
    union { unsigned int u; float f; } v; v.u = ((unsigned int)h) << 16;
    return v.f;
}
__device__ __forceinline__ void gld16(const void* g, void* l) {
    __builtin_amdgcn_global_load_lds(
        (const __attribute__((address_space(1))) void*)g,
        (__attribute__((address_space(3))) void*)l, 16, 0, 0);
}
#define MFMA16(a, b, c) __builtin_amdgcn_mfma_f32_16x16x32_bf16((a), (b), (c), 0, 0, 0)

// ---------------------------------------------------------------------------
// k_prep: per 64x64 tile of a [D][L] fp32 matrix: write bf16 cast copy
// ([d][l]) and bf16 transpose ([l][d], optional *scale[d]).
// ---------------------------------------------------------------------------
__global__ __launch_bounds__(256) void k_prep(
        const float* __restrict__ src, const float* __restrict__ scale,
        ushort_t* __restrict__ dst_cast, ushort_t* __restrict__ dst_t, int L) {
    __shared__ __align__(16) ushort_t lt[64 * 74];   // [d_local][c_local], pitch 74
    const int b = blockIdx.z, d0 = blockIdx.y * 64, l0 = blockIdx.x * 64;
    const int t = threadIdx.x;
    const int cp = t & 31;        // c-pair
    const int dr = t >> 5;        // 0..7
    const float* S = src + ((size_t)b * D_ + d0) * L + l0;
    #pragma unroll
    for (int i = 0; i < 8; ++i) {
        int d = i * 8 + dr;
        float2 v = *(const float2*)&S[(size_t)d * L + 2 * cp];
        unsigned int cpk = (unsigned int)f2bf(v.x) | ((unsigned int)f2bf(v.y) << 16);
        *(unsigned int*)(dst_cast + ((size_t)b * D_ + d0 + d) * L + l0 + 2 * cp) = cpk;
        float sc = scale ? scale[d0 + d] : 1.0f;
        unsigned int spk = (unsigned int)f2bf(v.x * sc) | ((unsigned int)f2bf(v.y * sc) << 16);
        *(unsigned int*)(lt + d * 74 + 2 * cp) = spk;
    }
    __syncthreads();
    const int c = t >> 2, dch = (t & 3) * 16;
    union { ushort_t u16[16]; uint4 u4[2]; } tmp;
    #pragma unroll
    for (int j = 0; j < 16; ++j) tmp.u16[j] = lt[(dch + j) * 74 + c];
    ushort_t* dr_ = dst_t + ((size_t)b * L + l0 + c) * D_ + d0 + dch;
    *(uint4*)dr_ = tmp.u4[0];
    *(uint4*)(dr_ + 8) = tmp.u4[1];
}

// ---------------------------------------------------------------------------
// k_subs: sub0[b,c], sub1[b,q] (+bias); also zero rowZ/colZ for the atomics.
// ---------------------------------------------------------------------------
__global__ __launch_bounds__(256) void k_subs(
        const float* __restrict__ C, const float* __restrict__ Q,
        const float* __restrict__ w4C, const float* __restrict__ w4Q,
        const float* __restrict__ bias,
        float* __restrict__ sub0, float* __restrict__ sub1,
        float* __restrict__ rowZ, float* __restrict__ colZ) {
    int bid = blockIdx.x;
    const int nb0 = B_ * (LC_ / 256);   // 128
    if (bid < nb0) {
        int b = bid / (LC_ / 256);
        int c = (bid % (LC_ / 256)) * 256 + threadIdx.x;
        const float* Cb = C + (size_t)b * D_ * LC_;
        float acc = 0.f;
        #pragma unroll 8
        for (int d = 0; d < D_; ++d) acc += Cb[(size_t)d * LC_ + c] * w4C[d];
        sub0[b * LC_ + c] = acc;
        rowZ[b * LC_ + c] = 0.f;
    } else {
        int id = bid - nb0;
        int b = id / (LQ_ / 256);
        int q = (id % (LQ_ / 256)) * 256 + threadIdx.x;
        const float* Qb = Q + (size_t)b * D_ * LQ_;
        float acc = bias[0];
        #pragma unroll 8
        for (int d = 0; d < D_; ++d) acc += Qb[(size_t)d * LQ_ + q] * w4Q[d];
        sub1[b * LQ_ + q] = acc;
        colZ[b * LQ_ + q] = 0.f;
    }
}

// ---------------------------------------------------------------------------
// k_score: 128x128 S-tile via MFMA (K=d=128). Epilogue: E=exp(S-SHIFT),
// store E[c][q] (q-masked) + Et[q][c] (c-masked) bf16, atomically accumulate
// rowZ (softmax-over-q denominator) and colZ (over c).
// grid (LQ/128, LC/128, B), 256 thr (4 waves, 2x2 of 64x64).
// ---------------------------------------------------------------------------
__global__ __launch_bounds__(256) void k_score(
        const ushort_t* __restrict__ Ct_bf, const ushort_t* __restrict__ Qt_bf,
        const float* __restrict__ sub0, const float* __restrict__ sub1,
        const int* __restrict__ Cmask, const int* __restrict__ Qmask,
        ushort_t* __restrict__ E_bf, ushort_t* __restrict__ Et_bf,
        float* __restrict__ rowZ, float* __restrict__ colZ) {
    __shared__ __align__(16) ushort_t As[128 * 128];
    __shared__ __align__(16) ushort_t Bs[128 * 128];
    __shared__ float s0s[128], s1s[128], cms[128], qms[128];
    const int b = blockIdx.z, c0 = blockIdx.y * 128, q0 = blockIdx.x * 128;
    const int tid = threadIdx.x, w = tid >> 6, lane = tid & 63;
    const int l15 = lane & 15, l4 = lane >> 4;
    const int wm = w >> 1, wn = w & 1;
    if (tid < 128) {
        s0s[tid] = sub0[b * LC_ + c0 + tid];
        cms[tid] = Cmask[b * LC_ + c0 + tid] ? 1.f : 0.f;
    } else {
        int t2 = tid - 128;
        s1s[t2] = sub1[b * LQ_ + q0 + t2];
        qms[t2] = Qmask[b * LQ_ + q0 + t2] ? 1.f : 0.f;
    }
    const ushort_t* Ab = Ct_bf + ((size_t)b * LC_ + c0) * D_;
    const ushort_t* Bb = Qt_bf + ((size_t)b * LQ_ + q0) * D_;
    #pragma unroll
    for (int i = 0; i < 8; ++i) {
        int r0 = w * 32 + i * 4;
        int row = r0 + l4;
        int ch = l15 ^ (row & 7);           // pre-swizzled source, linear LDS dest
        gld16(Ab + (size_t)row * 128 + ch * 8, As + r0 * 128);
        gld16(Bb + (size_t)row * 128 + ch * 8, Bs + r0 * 128);
    }
    __syncthreads();
    f32x4 acc[4][4];
    const f32x4 z4 = {0.f, 0.f, 0.f, 0.f};
    #pragma unroll
    for (int i = 0; i < 4; ++i)
        #pragma unroll
        for (int j = 0; j < 4; ++j) acc[i][j] = z4;
    #pragma unroll
    for (int ks = 0; ks < 4; ++ks) {
        short8 af[4], bfr[4];
        #pragma unroll
        for (int mi = 0; mi < 4; ++mi) {
            int row = wm * 64 + mi * 16 + l15;
            int ch = (ks * 4 + l4) ^ (row & 7);
            af[mi] = *(const short8*)(As + row * 128 + ch * 8);
        }
        #pragma unroll
        for (int ni = 0; ni < 4; ++ni) {
            int row = wn * 64 + ni * 16 + l15;
            int ch = (ks * 4 + l4) ^ (row & 7);
            bfr[ni] = *(const short8*)(Bs + row * 128 + ch * 8);
        }
        #pragma unroll
        for (int mi = 0; mi < 4; ++mi)
            #pragma unroll
            for (int ni = 0; ni < 4; ++ni)
                acc[mi][ni] = MFMA16(af[mi], bfr[ni], acc[mi][ni]);
    }
    // epilogue
    float rs[4][4];
    float cs[4] = {0.f, 0.f, 0.f, 0.f};
    #pragma unroll
    for (int mi = 0; mi < 4; ++mi)
        #pragma unroll
        for (int r = 0; r < 4; ++r) rs[mi][r] = 0.f;
    #pragma unroll
    for (int mi = 0; mi < 4; ++mi) {
        #pragma unroll
        for (int ni = 0; ni < 4; ++ni) {
            int q_l = wn * 64 + ni * 16 + l15;
            float qm = qms[q_l], s1v = s1s[q_l];
            ushort_t ets[4];
            #pragma unroll
            for (int r = 0; r < 4; ++r) {
                int c_l = wm * 64 + mi * 16 + l4 * 4 + r;
                float Sv = acc[mi][ni][r] + s0s[c_l] + s1v;
                float e = __expf(Sv - SHIFT_);
                ushort_t e1u = f2bf(e * qm);
                ushort_t e2u = f2bf(e * cms[c_l]);
                rs[mi][r] += bf2f(e1u);
                cs[ni] += bf2f(e2u);
                E_bf[((size_t)b * LC_ + c0 + c_l) * LQ_ + q0 + q_l] = e1u;
                ets[r] = e2u;
            }
            ushort4 etv = make_ushort4(ets[0], ets[1], ets[2], ets[3]);
            *(ushort4*)(Et_bf + ((size_t)b * LQ_ + q0 + q_l) * LC_ + c0 +
                        wm * 64 + mi * 16 + l4 * 4) = etv;
        }
    }
    #pragma unroll
    for (int mi = 0; mi < 4; ++mi)
        #pragma unroll
        for (int r = 0; r < 4; ++r) {
            float v = rs[mi][r];
            v += __shfl_xor(v, 1); v += __shfl_xor(v, 2);
            v += __shfl_xor(v, 4); v += __shfl_xor(v, 8);
            if (l15 == 0)
                atomicAdd(&rowZ[b * LC_ + c0 + wm * 64 + mi * 16 + l4 * 4 + r], v);
        }
    #pragma unroll
    for (int ni = 0; ni < 4; ++ni) {
        float v = cs[ni];
        v += __shfl_xor(v, 16); v += __shfl_xor(v, 32);
        if (l4 == 0)
            atomicAdd(&colZ[b * LQ_ + q0 + wn * 64 + ni * 16 + l15], v);
    }
}

// ---------------------------------------------------------------------------
// k_tpart: Tpart[sp][b][q][d] = sum_{c in chunk} Et[q][c] * Cb[d][c]  (MFMA)
// grid (LQ/128, nsplit, B), 256 thr.
// ---------------------------------------------------------------------------
__global__ __launch_bounds__(256) void k_tpart(
        const ushort_t* __restrict__ Et_bf, const ushort_t* __restrict__ Cb_bf,
        float* __restrict__ Tpart, int chunk) {
    __shared__ __align__(16) ushort_t As[128 * 64];
    __shared__ __align__(16) ushort_t Bs[128 * 64];
    const int b = blockIdx.z, sp = blockIdx.y, q0 = blockIdx.x * 128;
    const int tid = threadIdx.x, w = tid >> 6, lane = tid & 63;
    const int l15 = lane & 15, l4 = lane >> 4;
    const int l8 = lane >> 3, ch0 = lane & 7;
    const int wm = w >> 1, wn = w & 1;
    const int cbeg = sp * chunk;
    const ushort_t* Ab = Et_bf + ((size_t)b * LQ_ + q0) * LC_ + cbeg;
    const ushort_t* Bb = Cb_bf + (size_t)b * D_ * LC_ + cbeg;
    f32x4 acc[4][4];
    const f32x4 z4 = {0.f, 0.f, 0.f, 0.f};
    #pragma unroll
    for (int i = 0; i < 4; ++i)
        #pragma unroll
        for (int j = 0; j < 4; ++j) acc[i][j] = z4;
    for (int kk = 0; kk < chunk / 64; ++kk) {
        __syncthreads();
        #pragma unroll
        for (int i = 0; i < 4; ++i) {
            int r0 = w * 32 + i * 8;
            int row = r0 + l8;
            int ch = ch0 ^ (row & 7);
            gld16(Ab + (size_t)row * LC_ + kk * 64 + ch * 8, As + r0 * 64);
            gld16(Bb + (size_t)row * LC_ + kk * 64 + ch * 8, Bs + r0 * 64);
        }
        __syncthreads();
        #pragma unroll
        for (int ks = 0; ks < 2; ++ks) {
            short8 af[4], bfr[4];
            #pragma unroll
            for (int mi = 0; mi < 4; ++mi) {
                int row = wm * 64 + mi * 16 + l15;
                int ch = (ks * 4 + l4) ^ (row & 7);
                af[mi] = *(const short8*)(As + row * 64 + ch * 8);
            }
            #pragma unroll
            for (int ni = 0; ni < 4; ++ni) {
                int row = wn * 64 + ni * 16 + l15;
                int ch = (ks * 4 + l4) ^ (row & 7);
                bfr[ni] = *(const short8*)(Bs + row * 64 + ch * 8);
            }
            #pragma unroll
            for (int mi = 0; mi < 4; ++mi)
                #pragma unroll
                for (int ni = 0; ni < 4; ++ni)
                    acc[mi][ni] = MFMA16(af[mi], bfr[ni], acc[mi][ni]);
        }
    }
    float* Tp = Tpart + (((size_t)sp * B_ + b) * LQ_ + q0) * D_;
    #pragma unroll
    for (int mi = 0; mi < 4; ++mi)
        #pragma unroll
        for (int ni = 0; ni < 4; ++ni)
            #pragma unroll
            for (int r = 0; r < 4; ++r)
                Tp[(size_t)(wm * 64 + mi * 16 + l4 * 4 + r) * D_ +
                   wn * 64 + ni * 16 + l15] = acc[mi][ni][r];
}

// ---------------------------------------------------------------------------
// k_treduce: T'[b][d][q] = bf16( (1/colZ[q]) * sum_sp Tpart[sp][b][q][d] )
// grid (LQ/64, B), 256 thr; LDS transpose bounce.
// ---------------------------------------------------------------------------
__global__ __launch_bounds__(256) void k_treduce(
        const float* __restrict__ Tpart, const float* __restrict__ colZ,
        ushort_t* __restrict__ Tt_bf, int nsplit) {
    __shared__ __align__(16) ushort_t lt[128 * 72];   // [d][q], pitch 72
    const int b = blockIdx.y, q0 = blockIdx.x * 64;
    const int t = threadIdx.x;
    const int q = t >> 2, dp = t & 3;
    float r = 1.0f / colZ[b * LQ_ + q0 + q];
    const float4* base = (const float4*)(Tpart + ((size_t)b * LQ_ + q0 + q) * D_);
    const size_t spstr = (size_t)B_ * LQ_ * D_ / 4;
    #pragma unroll
    for (int i = 0; i < 8; ++i) {
        int d4 = dp + i * 4;
        float4 s = {0.f, 0.f, 0.f, 0.f};
        for (int sp = 0; sp < nsplit; ++sp) {
            float4 v = base[sp * spstr + d4];
            s.x += v.x; s.y += v.y; s.z += v.z; s.w += v.w;
        }
        int d = d4 * 4;
        lt[(d + 0) * 72 + q] = f2bf(s.x * r);
        lt[(d + 1) * 72 + q] = f2bf(s.y * r);
        lt[(d + 2) * 72 + q] = f2bf(s.z * r);
        lt[(d + 3) * 72 + q] = f2bf(s.w * r);
    }
    __syncthreads();
    const int d = t >> 1, half = t & 1;
    ushort_t* dst = Tt_bf + ((size_t)b * D_ + d) * LQ_ + q0 + half * 32;
    #pragma unroll
    for (int j = 0; j < 4; ++j)
        *(uint4*)(dst + j * 8) = *(const uint4*)(lt + d * 72 + half * 32 + j * 8);
}

// ---------------------------------------------------------------------------
// k_out: D1[d][c] = sum_q Qb[d][q]*E[c][q];  D2[d][c] = sum_q T'[d][q]*E[c][q]
// out = [Ct, A, Ct*A, Ct*Bm] with A = D1/rowZ, Bm = D2/rowZ.
// grid (LC/64, B), 256 thr. M=d(128), N=c(64), K=q=512 (8 iters of 64).
// ---------------------------------------------------------------------------
__global__ __launch_bounds__(256) void k_out(
        const ushort_t* __restrict__ E_bf, const ushort_t* __restrict__ Qb_bf,
        const ushort_t* __restrict__ Tt_bf, const float* __restrict__ C,
        const float* __restrict__ rowZ, float* __restrict__ out) {
    __shared__ __align__(16) ushort_t Qs[128 * 64];
    __shared__ __align__(16) ushort_t Ts[128 * 64];
    __shared__ __align__(16) ushort_t Es[64 * 64];
    __shared__ float rrs[64];
    const int b = blockIdx.y, c0 = blockIdx.x * 64;
    const int tid = threadIdx.x, w = tid >> 6, lane = tid & 63;
    const int l15 = lane & 15, l4 = lane >> 4;
    const int l8 = lane >> 3, ch0 = lane & 7;
    const int wm = w >> 1, wn = w & 1;
    if (tid < 64) rrs[tid] = 1.0f / rowZ[b * LC_ + c0 + tid];
    const ushort_t* Qb = Qb_bf + (size_t)b * D_ * LQ_;
    const ushort_t* Tb = Tt_bf + (size_t)b * D_ * LQ_;
    const ushort_t* Eb = E_bf + ((size_t)b * LC_ + c0) * LQ_;
    f32x4 accA[4][2], accB[4][2];
    const f32x4 z4 = {0.f, 0.f, 0.f, 0.f};
    #pragma unroll
    for (int i = 0; i < 4; ++i)
        #pragma unroll
        for (int j = 0; j < 2; ++j) { accA[i][j] = z4; accB[i][j] = z4; }
    for (int kk = 0; kk < 8; ++kk) {
        __syncthreads();
        #pragma unroll
        for (int i = 0; i < 4; ++i) {
            int r0 = w * 32 + i * 8;
            int row = r0 + l8;
            int ch = ch0 ^ (row & 7);
            gld16(Qb + (size_t)row * LQ_ + kk * 64 + ch * 8, Qs + r0 * 64);
            gld16(Tb + (size_t)row * LQ_ + kk * 64 + ch * 8, Ts + r0 * 64);
        }
        #pragma unroll
        for (int i = 0; i < 2; ++i) {
            int r0 = w * 16 + i * 8;
            int row = r0 + l8;
            int ch = ch0 ^ (row & 7);
            gld16(Eb + (size_t)row * LQ_ + kk * 64 + ch * 8, Es + r0 * 64);
        }
        __syncthreads();
        #pragma unroll
        for (int ks = 0; ks < 2; ++ks) {
            short8 aq[4], at[4], be[2];
            #pragma unroll
            for (int mi = 0; mi < 4; ++mi) {
                int row = wm * 64 + mi * 16 + l15;
                int ch = (ks * 4 + l4) ^ (row & 7);
                aq[mi] = *(const short8*)(Qs + row * 64 + ch * 8);
                at[mi] = *(const short8*)(Ts + row * 64 + ch * 8);
            }
            #pragma unroll
            for (int ni = 0; ni < 2; ++ni) {
                int row = wn * 32 + ni * 16 + l15;
                int ch = (ks * 4 + l4) ^ (row & 7);
                be[ni] = *(const short8*)(Es + row * 64 + ch * 8);
            }
            #pragma unroll
            for (int mi = 0; mi < 4; ++mi)
                #pragma unroll
                for (int ni = 0; ni < 2; ++ni) {
                    accA[mi][ni] = MFMA16(aq[mi], be[ni], accA[mi][ni]);
                    accB[mi][ni] = MFMA16(at[mi], be[ni], accB[mi][ni]);
                }
        }
    }
    #pragma unroll
    for (int mi = 0; mi < 4; ++mi)
        #pragma unroll
        for (int ni = 0; ni < 2; ++ni) {
            int c_l = wn * 32 + ni * 16 + l15;
            int cg = c0 + c_l;
            float rr = rrs[c_l];
            #pragma unroll
            for (int r = 0; r < 4; ++r) {
                int d = wm * 64 + mi * 16 + l4 * 4 + r;
                float ct = C[((size_t)b * D_ + d) * LC_ + cg];
                float av = accA[mi][ni][r] * rr;
                float bv = accB[mi][ni][r] * rr;
                size_t o = ((size_t)b * 4 * D_ + d) * LC_ + cg;
                out[o] = ct;
                out[o + (size_t)D_ * LC_] = av;
                out[o + (size_t)2 * D_ * LC_] = ct * av;
                out[o + (size_t)3 * D_ * LC_] = ct * bv;
            }
        }
}

// ---------------------------------------------------------------------------
extern "C" void kernel_launch(void* const* d_in, const int* in_sizes, int n_in,
                              void* d_out, int out_size, void* d_ws, size_t ws_size,
                              hipStream_t stream) {
    (void)in_sizes; (void)n_in; (void)out_size;
    const float* C     = (const float*)d_in[0];
    const float* Q     = (const float*)d_in[1];
    const int*   Cmask = (const int*)d_in[2];
    const int*   Qmask = (const int*)d_in[3];
    const float* w4C   = (const float*)d_in[4];
    const float* w4Q   = (const float*)d_in[5];
    const float* w4mlu = (const float*)d_in[6];
    const float* bias  = (const float*)d_in[7];
    float* out = (float*)d_out;

    char* p = (char*)d_ws;
    auto alloc = [&](size_t bytes) -> void* {
        void* r = (void*)p; p += (bytes + 255) & ~(size_t)255; return r;
    };
    ushort_t* Ct_bf = (ushort_t*)alloc((size_t)B_ * LC_ * D_ * 2);   // [b][c][d] *w4mlu
    ushort_t* Qt_bf = (ushort_t*)alloc((size_t)B_ * LQ_ * D_ * 2);   // [b][q][d]
    ushort_t* Cb_bf = (ushort_t*)alloc((size_t)B_ * D_ * LC_ * 2);   // [b][d][c]
    ushort_t* Qb_bf = (ushort_t*)alloc((size_t)B_ * D_ * LQ_ * 2);   // [b][d][q]
    ushort_t* E_bf  = (ushort_t*)alloc((size_t)B_ * LC_ * LQ_ * 2);  // exp, q-masked
    ushort_t* Et_bf = (ushort_t*)alloc((size_t)B_ * LQ_ * LC_ * 2);  // exp, c-masked
    ushort_t* Tt_bf = (ushort_t*)alloc((size_t)B_ * D_ * LQ_ * 2);   // [b][d][q]
    float* sub0 = (float*)alloc((size_t)B_ * LC_ * 4);
    float* sub1 = (float*)alloc((size_t)B_ * LQ_ * 4);
    float* rowZ = (float*)alloc((size_t)B_ * LC_ * 4);
    float* colZ = (float*)alloc((size_t)B_ * LQ_ * 4);
    size_t used = (size_t)(p - (char*)d_ws);
    size_t avail = ws_size > used ? ws_size - used : 0;
    int nsplit = 8;
    while (nsplit > 1 && (size_t)nsplit * B_ * LQ_ * D_ * 4 > avail) nsplit >>= 1;
    float* Tpart = (float*)alloc((size_t)nsplit * B_ * LQ_ * D_ * 4);
    int chunk = LC_ / nsplit;

    k_prep<<<dim3(LC_ / 64, 2, B_), 256, 0, stream>>>(C, w4mlu, Cb_bf, Ct_bf, LC_);
    k_prep<<<dim3(LQ_ / 64, 2, B_), 256, 0, stream>>>(Q, nullptr, Qb_bf, Qt_bf, LQ_);
    k_subs<<<B_ * (LC_ / 256) + B_ * (LQ_ / 256), 256, 0, stream>>>(
        C, Q, w4C, w4Q, bias, sub0, sub1, rowZ, colZ);
    k_score<<<dim3(LQ_ / 128, LC_ / 128, B_), 256, 0, stream>>>(
        Ct_bf, Qt_bf, sub0, sub1, Cmask, Qmask, E_bf, Et_bf, rowZ, colZ);
    k_tpart<<<dim3(LQ_ / 128, nsplit, B_), 256, 0, stream>>>(Et_bf, Cb_bf, Tpart, chunk);
    k_treduce<<<dim3(LQ_ / 64, B_), 256, 0, stream>>>(Tpart, colZ, Tt_bf, nsplit);
    k_out<<<dim3(LC_ / 64, B_), 256, 0, stream>>>(E_bf, Qb_bf, Tt_bf, C, rowZ, out);
}